// Round 7
// baseline (501.425 us; speedup 1.0000x reference)
//
#include <hip/hip_runtime.h>
#include <stdint.h>

#define S_LEN 2048
#define EMB   2048
#define NHEAD 32
#define HDIM  64
#define QKVN  3072   // 2048 q + 512 k + 512 v
#define KOFF  2048
#define VOFF  2560

typedef __attribute__((ext_vector_type(8))) short short8;
typedef __attribute__((ext_vector_type(4))) short short4v;
typedef __attribute__((ext_vector_type(4))) float f32x4;
typedef __attribute__((ext_vector_type(2))) float f32x2;

__device__ __forceinline__ unsigned short f2bf(float f) {
  union { float f; unsigned u; } v; v.f = f;
  return (unsigned short)((v.u + 0x7fffu + ((v.u >> 16) & 1u)) >> 16);
}

__device__ __forceinline__ f32x4 mfma16(short8 a, short8 b, f32x4 c) {
  return __builtin_amdgcn_mfma_f32_16x16x32_bf16(a, b, c, 0, 0, 0);
}

__device__ __forceinline__ void gload_lds16(const void* g, void* l) {
  __builtin_amdgcn_global_load_lds(
      (const __attribute__((address_space(1))) void*)g,
      (__attribute__((address_space(3))) void*)l, 16, 0, 0);
}

__device__ __forceinline__ unsigned cvt_pk_bf16(float lo, float hi) {
  unsigned r;
  asm("v_cvt_pk_bf16_f32 %0, %1, %2" : "=v"(r) : "v"(lo), "v"(hi));
  return r;
}

__device__ __forceinline__ float bperm_f32(int idx_bytes, float v) {
  int r = __builtin_amdgcn_ds_bpermute(idx_bytes, __builtin_bit_cast(int, v));
  return __builtin_bit_cast(float, r);
}

__device__ __forceinline__ float bf16lo_f32(unsigned u) {
  return __builtin_bit_cast(float, u << 16);
}
__device__ __forceinline__ float bf16hi_f32(unsigned u) {
  return __builtin_bit_cast(float, u & 0xffff0000u);
}

// ---------------- fused fp32 -> bf16 convert (all 5 tensors) ----------------
__global__ __launch_bounds__(256) void k_cvt_all(
    const float* __restrict__ x, const float* __restrict__ Wq,
    const float* __restrict__ Wk, const float* __restrict__ Wv,
    const float* __restrict__ Wo, unsigned short* __restrict__ xb,
    unsigned short* __restrict__ wqkv, unsigned short* __restrict__ wob) {
  long i = (long)(blockIdx.x * blockDim.x + threadIdx.x) * 4;
  const float* src; unsigned short* dst; long off;
  if (i < 4194304L)       { src = x;  dst = xb;             off = i; }
  else if (i < 8388608L)  { src = Wq; dst = wqkv;           off = i - 4194304L; }
  else if (i < 9437184L)  { src = Wk; dst = wqkv + 4194304; off = i - 8388608L; }
  else if (i < 10485760L) { src = Wv; dst = wqkv + 5242880; off = i - 9437184L; }
  else                    { src = Wo; dst = wob;            off = i - 10485760L; }
  float4 v = *reinterpret_cast<const float4*>(src + off);
  short4v o;
  o.x = (short)f2bf(v.x); o.y = (short)f2bf(v.y);
  o.z = (short)f2bf(v.z); o.w = (short)f2bf(v.w);
  *reinterpret_cast<short4v*>(dst + off) = o;
}

__global__ void k_bias_cat(const float* __restrict__ bq, const float* __restrict__ bk,
                           const float* __restrict__ bv, float* __restrict__ dst) {
  int i = blockIdx.x * blockDim.x + threadIdx.x;   // grid covers exactly 3072
  if (i < 2048) dst[i] = bq[i];
  else if (i < 2560) dst[i] = bk[i - 2048];
  else dst[i] = bv[i - 2560];
}

// ---------------- GEMM: C[M,N] = A[M,K] @ B[N,K]^T + bias ----------------
template <typename OUT_T>
__global__ __launch_bounds__(256) void k_gemm_bt(
    const unsigned short* __restrict__ A, const unsigned short* __restrict__ B,
    const float* __restrict__ bias, OUT_T* __restrict__ C, int M, int N, int K) {
  __shared__ unsigned short As[128 * 32];
  __shared__ unsigned short Bs[128 * 32];
  const int t = threadIdx.x;
  const int l = t & 63;
  const int w = t >> 6;
  const int m0 = blockIdx.x * 128;
  const int n0 = blockIdx.y * 128;
  const int wm = w >> 1, wn = w & 1;

  f32x4 acc[4][4] = {};

  const unsigned short* ga0 = A + (size_t)(m0 + (t >> 2)) * K + (t & 3) * 8;
  const unsigned short* ga1 = ga0 + (size_t)64 * K;
  const unsigned short* gb0 = B + (size_t)(n0 + (t >> 2)) * K + (t & 3) * 8;
  const unsigned short* gb1 = gb0 + (size_t)64 * K;
  unsigned short* la0 = As + t * 8;
  unsigned short* la1 = As + 2048 + t * 8;
  unsigned short* lb0 = Bs + t * 8;
  unsigned short* lb1 = Bs + 2048 + t * 8;

  const int lr = l & 15;
  const int lk = (l >> 4) * 8;
  const unsigned short* arow = As + (wm * 64 + lr) * 32 + lk;
  const unsigned short* brow = Bs + (wn * 64 + lr) * 32 + lk;

  for (int k0 = 0; k0 < K; k0 += 32) {
    gload_lds16(ga0, la0);
    gload_lds16(ga1, la1);
    gload_lds16(gb0, lb0);
    gload_lds16(gb1, lb1);
    ga0 += 32; ga1 += 32; gb0 += 32; gb1 += 32;
    __syncthreads();
    short8 af[4], bfv[4];
#pragma unroll
    for (int i = 0; i < 4; i++) {
      af[i]  = *reinterpret_cast<const short8*>(arow + i * 16 * 32);
      bfv[i] = *reinterpret_cast<const short8*>(brow + i * 16 * 32);
    }
#pragma unroll
    for (int i = 0; i < 4; i++)
#pragma unroll
      for (int j = 0; j < 4; j++)
        acc[i][j] = mfma16(af[i], bfv[j], acc[i][j]);
    __syncthreads();
  }

  const int lg = l >> 4;
#pragma unroll
  for (int i = 0; i < 4; i++) {
#pragma unroll
    for (int j = 0; j < 4; j++) {
      int col = n0 + wn * 64 + j * 16 + lr;
      float bb = bias[col];
#pragma unroll
      for (int r = 0; r < 4; r++) {
        int row = m0 + wm * 64 + i * 16 + lg * 4 + r;
        float val = acc[i][j][r] + bb;
        if constexpr (sizeof(OUT_T) == 2)
          C[(size_t)row * N + col] = (OUT_T)f2bf(val);
        else
          C[(size_t)row * N + col] = (OUT_T)val;
      }
    }
  }
}

// ---------------- V transpose: vT[gd][pos] = qkv[pos][VOFF+gd] ----------------
__global__ __launch_bounds__(256) void k_vT(const unsigned short* __restrict__ qkv,
                                            unsigned short* __restrict__ vT) {
  __shared__ unsigned short tile[64][72];
  const int t = threadIdx.x;
  const int p0 = (blockIdx.x & 31) * 64;
  const int g0 = (blockIdx.x >> 5) * 64;
  {
    const int pl = t >> 3;
    const int gl = (t & 7) * 8;
#pragma unroll
    for (int i = 0; i < 2; i++) {
      int p = pl + i * 32;
      short8 v = *reinterpret_cast<const short8*>(qkv + (size_t)(p0 + p) * QKVN + VOFF + g0 + gl);
#pragma unroll
      for (int j = 0; j < 8; j++) tile[p][gl + j] = (unsigned short)v[j];
    }
  }
  __syncthreads();
  {
    const int gr = t >> 3;
    const int pc = (t & 7) * 8;
#pragma unroll
    for (int i = 0; i < 2; i++) {
      int g = gr + i * 32;
      short8 o;
#pragma unroll
      for (int j = 0; j < 8; j++) o[j] = (short)tile[pc + j][g];
      *reinterpret_cast<short8*>(vT + (size_t)(g0 + g) * S_LEN + p0 + pc) = o;
    }
  }
}

// ---------------- fused attention v7: stores LAST (decoupled from vmcnt) ----
// v6 structure (P in regs via swapped QK^T; PV via 16x16x32 k-relabeling;
// full-line nt attn_w stores via bpermute repack) with one structural change:
// the 128KB/block attn_w store phase moves to the very END of the kernel.
// vmcnt is an in-issue-order counter, so any load-wait after the stores
// forced the store drain into the block's critical path (the r6 binder).
// With stores last, the wave issues them and retires; drain overlaps the
// next block's compute. attn_w values are expanded from the same bf16 pa8
// fragments PV consumed (error +~2e-4, inside threshold).
__global__ __launch_bounds__(512, 4) void k_attn(
    const unsigned short* __restrict__ qkv, const unsigned short* __restrict__ vT,
    float* __restrict__ attn_w, unsigned short* __restrict__ hout) {
  __shared__ float red_mx[8 * 16];
  __shared__ float red_sm[8 * 16];
  __shared__ float pvred[8][16][68];    // [wave][q][hd] + pad

  const int t = threadIdx.x;
  const int l = t & 63;
  const int w = t >> 6;               // 8 waves
  const int h = blockIdx.x >> 7;      // head
  const int r0 = (blockIdx.x & 127) * 16;
  const int g = h >> 2;               // kv group
  const int lr = l & 15;
  const int lg = l >> 4;              // 0..3
  const int lk = lg * 8;

  // Q fragment = B operand of QK^T: col/q-row r0+lr, k = lk..lk+7 (+32)
  const unsigned short* qbase = qkv + (size_t)(r0 + lr) * QKVN + h * HDIM + lk;
  const short8 bq0 = *reinterpret_cast<const short8*>(qbase);
  const short8 bq1 = *reinterpret_cast<const short8*>(qbase + 32);

  // ---- scores^T in regs: acc[i] = P-chunk, cols w*256 + i*16 + lg*4 + {0..3} ----
  f32x4 acc[16];
  const unsigned short* kbase =
      qkv + (size_t)KOFF + g * HDIM + lk + (size_t)(w * 256 + lr) * QKVN;
#pragma unroll
  for (int i = 0; i < 16; i++) {
    const unsigned short* kp = kbase + (size_t)(i * 16) * QKVN;
    short8 a0 = *reinterpret_cast<const short8*>(kp);
    short8 a1 = *reinterpret_cast<const short8*>(kp + 32);
    f32x4 a = {};
    a = mfma16(a0, bq0, a);
    a = mfma16(a1, bq1, a);
    acc[i] = a * 0.125f;
  }

  // ---- row max (all of a lane's values belong to q-row r0+lr) ----
  float mx = -1e30f;
#pragma unroll
  for (int i = 0; i < 16; i++)
    mx = fmaxf(mx, fmaxf(fmaxf(acc[i][0], acc[i][1]), fmaxf(acc[i][2], acc[i][3])));
  mx = fmaxf(mx, __shfl_xor(mx, 16, 64));
  mx = fmaxf(mx, __shfl_xor(mx, 32, 64));
  if (l < 16) red_mx[w * 16 + l] = mx;
  __syncthreads();
  float bm = red_mx[lr];
#pragma unroll
  for (int j = 1; j < 8; j++) bm = fmaxf(bm, red_mx[j * 16 + lr]);

  // ---- single exp pass + row sum ----
  float sm = 0.f;
#pragma unroll
  for (int i = 0; i < 16; i++) {
#pragma unroll
    for (int r = 0; r < 4; r++) {
      float e = __expf(acc[i][r] - bm);
      acc[i][r] = e;
      sm += e;
    }
  }
  sm += __shfl_xor(sm, 16, 64);
  sm += __shfl_xor(sm, 32, 64);
  if (l < 16) red_sm[w * 16 + l] = sm;
  __syncthreads();
  float bs = 0.f;
#pragma unroll
  for (int j = 0; j < 8; j++) bs += red_sm[j * 16 + lr];
  const float inv = 1.0f / bs;

  // ---- normalize + pack bf16 A-frags; acc dies here ----
  union A8 { short8 s; unsigned u[4]; } pa8[8];
#pragma unroll
  for (int i = 0; i < 16; i++) {
    f32x4 p = acc[i] * inv;
    pa8[i >> 1].u[(i & 1) * 2 + 0] = cvt_pk_bf16(p[0], p[1]);
    pa8[i >> 1].u[(i & 1) * 2 + 1] = cvt_pk_bf16(p[2], p[3]);
  }

  // ---- PV from registers: wave's own 256-k stripe, all 4 hd-tiles ----
  const unsigned short* vtb =
      vT + (size_t)(g * HDIM + lr) * S_LEN + w * 256 + lg * 4;
  const unsigned short* vtb1 = vtb + (size_t)16 * S_LEN;
  const unsigned short* vtb2 = vtb + (size_t)32 * S_LEN;
  const unsigned short* vtb3 = vtb + (size_t)48 * S_LEN;
  f32x4 pv0 = {}, pv1 = {}, pv2 = {}, pv3 = {};
#pragma unroll
  for (int s = 0; s < 8; s++) {
    const int base = s * 32;
    union A8 b0, b1, b2, b3;
    *reinterpret_cast<short4v*>(&b0.u[0]) = *reinterpret_cast<const short4v*>(vtb  + base);
    *reinterpret_cast<short4v*>(&b0.u[2]) = *reinterpret_cast<const short4v*>(vtb  + base + 16);
    *reinterpret_cast<short4v*>(&b1.u[0]) = *reinterpret_cast<const short4v*>(vtb1 + base);
    *reinterpret_cast<short4v*>(&b1.u[2]) = *reinterpret_cast<const short4v*>(vtb1 + base + 16);
    *reinterpret_cast<short4v*>(&b2.u[0]) = *reinterpret_cast<const short4v*>(vtb2 + base);
    *reinterpret_cast<short4v*>(&b2.u[2]) = *reinterpret_cast<const short4v*>(vtb2 + base + 16);
    *reinterpret_cast<short4v*>(&b3.u[0]) = *reinterpret_cast<const short4v*>(vtb3 + base);
    *reinterpret_cast<short4v*>(&b3.u[2]) = *reinterpret_cast<const short4v*>(vtb3 + base + 16);
    pv0 = mfma16(pa8[s].s, b0.s, pv0);
    pv1 = mfma16(pa8[s].s, b1.s, pv1);
    pv2 = mfma16(pa8[s].s, b2.s, pv2);
    pv3 = mfma16(pa8[s].s, b3.s, pv3);
  }
  // lane holds out_partial[q = lg*4+r][hd = ht*16+lr]
#pragma unroll
  for (int r = 0; r < 4; r++) {
    pvred[w][lg * 4 + r][lr]      = pv0[r];
    pvred[w][lg * 4 + r][16 + lr] = pv1[r];
    pvred[w][lg * 4 + r][32 + lr] = pv2[r];
    pvred[w][lg * 4 + r][48 + lr] = pv3[r];
  }
  __syncthreads();   // PV loads already consumed; no stores pending -> cheap

  // ---- cross-wave reduce + hout write: 2 outputs per thread ----
  {
    const int q = t >> 5;
    const int hd = (t & 31) * 2;
    float s0 = 0.f, s1 = 0.f;
#pragma unroll
    for (int s = 0; s < 8; s++) {
      f32x2 v = *reinterpret_cast<const f32x2*>(&pvred[s][q][hd]);
      s0 += v.x; s1 += v.y;
    }
    union { unsigned u; unsigned short s[2]; } o;
    o.s[0] = f2bf(s0); o.s[1] = f2bf(s1);
    *reinterpret_cast<unsigned*>(
        &hout[(size_t)(r0 + q) * EMB + h * HDIM + hd]) = o.u;
  }

  // ---- attn_w store LAST: expand pa8 bf16->f32, bpermute repack, nt full
  // lines. Nothing after these stores -> no vmcnt wait; wave retires and the
  // drain overlaps the next block's compute.
  {
    const int jj = l & 7;              // col-quad within 32-col line
    const int rown = l >> 3;           // row within 8-row half
    const int idx0 = ((l & 3) * 16 + rown) * 4;   // source lane (rows 0-7)
    const int idx1 = idx0 + 32;                   // rows 8-15
    const bool hiq = (l & 4) != 0;
    float* b0 = attn_w + (size_t)h * S_LEN * S_LEN
              + (size_t)(r0 + rown) * S_LEN + w * 256 + jj * 4;
    float* b1 = b0 + 8 * S_LEN;
#pragma unroll
    for (int s = 0; s < 8; s++) {
      f32x4 X, Y;
      X[0] = bf16lo_f32(pa8[s].u[0]); X[1] = bf16hi_f32(pa8[s].u[0]);
      X[2] = bf16lo_f32(pa8[s].u[1]); X[3] = bf16hi_f32(pa8[s].u[1]);
      Y[0] = bf16lo_f32(pa8[s].u[2]); Y[1] = bf16hi_f32(pa8[s].u[2]);
      Y[2] = bf16lo_f32(pa8[s].u[3]); Y[3] = bf16hi_f32(pa8[s].u[3]);
      f32x4 o0, o1;
#pragma unroll
      for (int c = 0; c < 4; c++) {
        float x0 = bperm_f32(idx0, X[c]);
        float y0 = bperm_f32(idx0, Y[c]);
        o0[c] = hiq ? y0 : x0;
        float x1 = bperm_f32(idx1, X[c]);
        float y1 = bperm_f32(idx1, Y[c]);
        o1[c] = hiq ? y1 : x1;
      }
      __builtin_nontemporal_store(o0, reinterpret_cast<f32x4*>(b0 + s * 32));
      __builtin_nontemporal_store(o1, reinterpret_cast<f32x4*>(b1 + s * 32));
    }
  }
}

extern "C" void kernel_launch(void* const* d_in, const int* in_sizes, int n_in,
                              void* d_out, int out_size, void* d_ws, size_t ws_size,
                              hipStream_t stream) {
  const float* x  = (const float*)d_in[0];
  const float* Wq = (const float*)d_in[1];
  const float* bq = (const float*)d_in[2];
  const float* Wk = (const float*)d_in[3];
  const float* bk = (const float*)d_in[4];
  const float* Wv = (const float*)d_in[5];
  const float* bv = (const float*)d_in[6];
  const float* Wo = (const float*)d_in[7];
  const float* bo = (const float*)d_in[8];
  float* out = (float*)d_out;

  char* ws = (char*)d_ws;
  unsigned short* x_bf  = (unsigned short*)(ws);                 // 8 MiB
  unsigned short* wqkv  = (unsigned short*)(ws + (8ull  << 20)); // 12 MiB
  unsigned short* wo_bf = (unsigned short*)(ws + (20ull << 20)); // 8 MiB
  float*          bqkv  = (float*)         (ws + (28ull << 20)); // 12 KiB
  unsigned short* qkv   = (unsigned short*)(ws + (29ull << 20)); // 12 MiB
  unsigned short* vT    = (unsigned short*)(ws + (41ull << 20)); // 2 MiB
  unsigned short* hout  = (unsigned short*)(ws + (43ull << 20)); // 8 MiB

  k_cvt_all<<<14336, 256, 0, stream>>>(x, Wq, Wk, Wv, Wo, x_bf, wqkv, wo_bf);
  k_bias_cat<<<12, 256, 0, stream>>>(bq, bk, bv, bqkv);

  dim3 g1(16, 24);  // M/128 x N/128
  k_gemm_bt<unsigned short><<<g1, 256, 0, stream>>>(x_bf, wqkv, bqkv, qkv, 2048, 3072, 2048);
  k_vT<<<256, 256, 0, stream>>>(qkv, vT);
  k_attn<<<4096, 512, 0, stream>>>(qkv, vT, out, hout);
  dim3 g2(16, 16);
  k_gemm_bt<float><<<g2, 256, 0, stream>>>(hout, wo_bf, bo, out + (size_t)NHEAD * S_LEN * S_LEN, 2048, 2048, 2048);
}

// Round 8
// 471.525 us; speedup vs baseline: 1.0634x; 1.0634x over previous
//
#include <hip/hip_runtime.h>
#include <stdint.h>

#define S_LEN 2048
#define EMB   2048
#define NHEAD 32
#define HDIM  64
#define QKVN  3072   // 2048 q + 512 k + 512 v
#define KOFF  2048
#define VOFF  2560

typedef __attribute__((ext_vector_type(8))) short short8;
typedef __attribute__((ext_vector_type(4))) short short4v;
typedef __attribute__((ext_vector_type(4))) float f32x4;

__device__ __forceinline__ unsigned short f2bf(float f) {
  union { float f; unsigned u; } v; v.f = f;
  return (unsigned short)((v.u + 0x7fffu + ((v.u >> 16) & 1u)) >> 16);
}

__device__ __forceinline__ f32x4 mfma16(short8 a, short8 b, f32x4 c) {
  return __builtin_amdgcn_mfma_f32_16x16x32_bf16(a, b, c, 0, 0, 0);
}

__device__ __forceinline__ void gload_lds16(const void* g, void* l) {
  __builtin_amdgcn_global_load_lds(
      (const __attribute__((address_space(1))) void*)g,
      (__attribute__((address_space(3))) void*)l, 16, 0, 0);
}

__device__ __forceinline__ unsigned cvt_pk_bf16(float lo, float hi) {
  unsigned r;
  asm("v_cvt_pk_bf16_f32 %0, %1, %2" : "=v"(r) : "v"(lo), "v"(hi));
  return r;
}

__device__ __forceinline__ float bperm_f32(int idx_bytes, float v) {
  int r = __builtin_amdgcn_ds_bpermute(idx_bytes, __builtin_bit_cast(int, v));
  return __builtin_bit_cast(float, r);
}

__device__ __forceinline__ float bf16lo_f32(unsigned u) {
  return __builtin_bit_cast(float, u << 16);
}
__device__ __forceinline__ float bf16hi_f32(unsigned u) {
  return __builtin_bit_cast(float, u & 0xffff0000u);
}

// ---------------- fused fp32 -> bf16 convert (all 5 tensors) ----------------
__global__ __launch_bounds__(256) void k_cvt_all(
    const float* __restrict__ x, const float* __restrict__ Wq,
    const float* __restrict__ Wk, const float* __restrict__ Wv,
    const float* __restrict__ Wo, unsigned short* __restrict__ xb,
    unsigned short* __restrict__ wqkv, unsigned short* __restrict__ wob) {
  long i = (long)(blockIdx.x * blockDim.x + threadIdx.x) * 4;
  const float* src; unsigned short* dst; long off;
  if (i < 4194304L)       { src = x;  dst = xb;             off = i; }
  else if (i < 8388608L)  { src = Wq; dst = wqkv;           off = i - 4194304L; }
  else if (i < 9437184L)  { src = Wk; dst = wqkv + 4194304; off = i - 8388608L; }
  else if (i < 10485760L) { src = Wv; dst = wqkv + 5242880; off = i - 9437184L; }
  else                    { src = Wo; dst = wob;            off = i - 10485760L; }
  float4 v = *reinterpret_cast<const float4*>(src + off);
  short4v o;
  o.x = (short)f2bf(v.x); o.y = (short)f2bf(v.y);
  o.z = (short)f2bf(v.z); o.w = (short)f2bf(v.w);
  *reinterpret_cast<short4v*>(dst + off) = o;
}

__global__ void k_bias_cat(const float* __restrict__ bq, const float* __restrict__ bk,
                           const float* __restrict__ bv, float* __restrict__ dst) {
  int i = blockIdx.x * blockDim.x + threadIdx.x;   // grid covers exactly 3072
  if (i < 2048) dst[i] = bq[i];
  else if (i < 2560) dst[i] = bk[i - 2048];
  else dst[i] = bv[i - 2560];
}

// ---------------- GEMM: C[M,N] = A[M,K] @ B[N,K]^T + bias ----------------
template <typename OUT_T>
__global__ __launch_bounds__(256) void k_gemm_bt(
    const unsigned short* __restrict__ A, const unsigned short* __restrict__ B,
    const float* __restrict__ bias, OUT_T* __restrict__ C, int M, int N, int K) {
  __shared__ unsigned short As[128 * 32];
  __shared__ unsigned short Bs[128 * 32];
  const int t = threadIdx.x;
  const int l = t & 63;
  const int w = t >> 6;
  const int m0 = blockIdx.x * 128;
  const int n0 = blockIdx.y * 128;
  const int wm = w >> 1, wn = w & 1;

  f32x4 acc[4][4] = {};

  const unsigned short* ga0 = A + (size_t)(m0 + (t >> 2)) * K + (t & 3) * 8;
  const unsigned short* ga1 = ga0 + (size_t)64 * K;
  const unsigned short* gb0 = B + (size_t)(n0 + (t >> 2)) * K + (t & 3) * 8;
  const unsigned short* gb1 = gb0 + (size_t)64 * K;
  unsigned short* la0 = As + t * 8;
  unsigned short* la1 = As + 2048 + t * 8;
  unsigned short* lb0 = Bs + t * 8;
  unsigned short* lb1 = Bs + 2048 + t * 8;

  const int lr = l & 15;
  const int lk = (l >> 4) * 8;
  const unsigned short* arow = As + (wm * 64 + lr) * 32 + lk;
  const unsigned short* brow = Bs + (wn * 64 + lr) * 32 + lk;

  for (int k0 = 0; k0 < K; k0 += 32) {
    gload_lds16(ga0, la0);
    gload_lds16(ga1, la1);
    gload_lds16(gb0, lb0);
    gload_lds16(gb1, lb1);
    ga0 += 32; ga1 += 32; gb0 += 32; gb1 += 32;
    __syncthreads();
    short8 af[4], bfv[4];
#pragma unroll
    for (int i = 0; i < 4; i++) {
      af[i]  = *reinterpret_cast<const short8*>(arow + i * 16 * 32);
      bfv[i] = *reinterpret_cast<const short8*>(brow + i * 16 * 32);
    }
#pragma unroll
    for (int i = 0; i < 4; i++)
#pragma unroll
      for (int j = 0; j < 4; j++)
        acc[i][j] = mfma16(af[i], bfv[j], acc[i][j]);
    __syncthreads();
  }

  const int lg = l >> 4;
#pragma unroll
  for (int i = 0; i < 4; i++) {
#pragma unroll
    for (int j = 0; j < 4; j++) {
      int col = n0 + wn * 64 + j * 16 + lr;
      float bb = bias[col];
#pragma unroll
      for (int r = 0; r < 4; r++) {
        int row = m0 + wm * 64 + i * 16 + lg * 4 + r;
        float val = acc[i][j][r] + bb;
        if constexpr (sizeof(OUT_T) == 2)
          C[(size_t)row * N + col] = (OUT_T)f2bf(val);
        else
          C[(size_t)row * N + col] = (OUT_T)val;
      }
    }
  }
}

// ---------------- V transpose (PERMUTED layout for 16B PV B-frags) ----------
// vT2[gd][32b + r'] = V[32b + sigma(r')][gd], sigma(r') for r' = lgp*8+jj:
//   jj<4 -> lgp*4+jj ; jj>=4 -> 16 + lgp*4 + (jj-4)
// so PV's B-frag (kappa = lg*8+j) is ONE contiguous 16B load at col lg*8.
__global__ __launch_bounds__(256) void k_vT(const unsigned short* __restrict__ qkv,
                                            unsigned short* __restrict__ vT) {
  __shared__ unsigned short tile[64][72];
  const int t = threadIdx.x;
  const int p0 = (blockIdx.x & 31) * 64;
  const int g0 = (blockIdx.x >> 5) * 64;
  {
    const int pl = t >> 3;
    const int gl = (t & 7) * 8;
#pragma unroll
    for (int i = 0; i < 2; i++) {
      int p = pl + i * 32;
      short8 v = *reinterpret_cast<const short8*>(qkv + (size_t)(p0 + p) * QKVN + VOFF + g0 + gl);
#pragma unroll
      for (int j = 0; j < 8; j++) tile[p][gl + j] = (unsigned short)v[j];
    }
  }
  __syncthreads();
  {
    const int gr = t >> 3;
    const int pc = (t & 7) * 8;
    const int cb = pc & ~31;
    const int rbase = pc & 31;           // 0,8,16,24
#pragma unroll
    for (int i = 0; i < 2; i++) {
      int g = gr + i * 32;
      short8 o;
#pragma unroll
      for (int j = 0; j < 8; j++) {
        int rp = rbase + j;              // r' in [0,32)
        int q8 = rp >> 3, jj = rp & 7;
        int src = cb + ((jj < 4) ? (q8 * 4 + jj) : (16 + q8 * 4 + (jj - 4)));
        o[j] = (short)tile[src][g];
      }
      *reinterpret_cast<short8*>(vT + (size_t)(g0 + g) * S_LEN + p0 + pc) = o;
    }
  }
}

// ---------------- fused attention v8: independent waves, zero LDS -----------
// One WAVE = one (head, 16 q-rows), full 2048-k range, chunks of 128 cols.
// Two passes: A = QK^T + online row max/sum (in-register; row-reduce is two
// shfl_xor since a lane's values all belong to q-row l&15). B = recompute
// QK^T (identical instructions -> identical values), normalize with final
// (m, 1/sm), pack pa8 bf16, PV-accumulate (16 AGPR, k-relabeled 16x16x32 as
// in v5-v7), bpermute full-line store of the attn chunk. No barriers, no
// __shared__, no cross-wave anything. Blocks = 4 waves, XCD-swizzled so each
// XCD serves exactly one KV group (512 KB << 4 MiB XCD L2).
__global__ __launch_bounds__(256, 4) void k_attn(
    const unsigned short* __restrict__ qkv, const unsigned short* __restrict__ vT,
    float* __restrict__ attn_w, unsigned short* __restrict__ hout) {
  const int t = threadIdx.x;
  const int l = t & 63;
  const int wv = t >> 6;                    // wave in block (0..3)
  const int bid = blockIdx.x;               // 0..1023
  const int lb = (bid & 7) * 128 + (bid >> 3);   // XCD-contiguous remap
  const int gw = lb * 4 + wv;               // global wave id 0..4095
  const int h = gw >> 7;                    // head
  const int r0 = (gw & 127) * 16;           // q-row base
  const int g = h >> 2;                     // kv group
  const int lr = l & 15;
  const int lg = l >> 4;                    // 0..3
  const int lk = lg * 8;

  // Q fragment = B operand of QK^T (rows r0+lr)
  const unsigned short* qbase = qkv + (size_t)(r0 + lr) * QKVN + h * HDIM + lk;
  const short8 bq0 = *reinterpret_cast<const short8*>(qbase);
  const short8 bq1 = *reinterpret_cast<const short8*>(qbase + 32);

  const unsigned short* kcol = qkv + (size_t)KOFF + g * HDIM + lk;

  // ---- pass A: online row max + sum over 16 chunks of 128 cols ----
  float m = -1e30f, sm = 0.f;
  for (int c = 0; c < 16; ++c) {
    const unsigned short* kp0 = kcol + (size_t)(c * 128 + lr) * QKVN;
    f32x4 acc[8];
#pragma unroll
    for (int i = 0; i < 8; ++i) {
      const unsigned short* kp = kp0 + (size_t)(i * 16) * QKVN;
      short8 a0 = *reinterpret_cast<const short8*>(kp);
      short8 a1 = *reinterpret_cast<const short8*>(kp + 32);
      f32x4 a = {};
      a = mfma16(a0, bq0, a);
      a = mfma16(a1, bq1, a);
      acc[i] = a * 0.125f;
    }
    float mc = -1e30f;
#pragma unroll
    for (int i = 0; i < 8; ++i)
      mc = fmaxf(mc, fmaxf(fmaxf(acc[i][0], acc[i][1]), fmaxf(acc[i][2], acc[i][3])));
    mc = fmaxf(mc, __shfl_xor(mc, 16, 64));
    mc = fmaxf(mc, __shfl_xor(mc, 32, 64));
    float nm = fmaxf(m, mc);
    float ps = 0.f;
#pragma unroll
    for (int i = 0; i < 8; ++i) {
#pragma unroll
      for (int r = 0; r < 4; ++r) ps += __expf(acc[i][r] - nm);
    }
    ps += __shfl_xor(ps, 16, 64);
    ps += __shfl_xor(ps, 32, 64);
    sm = sm * __expf(m - nm) + ps;
    m = nm;
  }
  const float inv = 1.0f / sm;

  // ---- pass B: recompute, normalize, PV, store ----
  f32x4 pv0 = {}, pv1 = {}, pv2 = {}, pv3 = {};
  const unsigned short* vt0 = vT + (size_t)(g * HDIM + lr) * S_LEN + lk;
  const unsigned short* vt1 = vt0 + (size_t)16 * S_LEN;
  const unsigned short* vt2 = vt0 + (size_t)32 * S_LEN;
  const unsigned short* vt3 = vt0 + (size_t)48 * S_LEN;

  // bpermute store constants
  const int jj = l & 7;
  const int rown = l >> 3;
  const int idx0 = ((l & 3) * 16 + rown) * 4;   // source lane (rows 0-7)
  const int idx1 = idx0 + 32;                   // rows 8-15
  const bool hiq = (l & 4) != 0;
  float* arow0 = attn_w + (size_t)h * S_LEN * S_LEN
               + (size_t)(r0 + rown) * S_LEN + jj * 4;
  float* arow1 = arow0 + 8 * S_LEN;

  for (int c = 0; c < 16; ++c) {
    const int kc = c * 128;
    const unsigned short* kp0 = kcol + (size_t)(kc + lr) * QKVN;
    union A8 { short8 s; unsigned u[4]; } pa8[4];
#pragma unroll
    for (int i = 0; i < 8; ++i) {
      const unsigned short* kp = kp0 + (size_t)(i * 16) * QKVN;
      short8 a0 = *reinterpret_cast<const short8*>(kp);
      short8 a1 = *reinterpret_cast<const short8*>(kp + 32);
      f32x4 a = {};
      a = mfma16(a0, bq0, a);
      a = mfma16(a1, bq1, a);
      float p0 = __expf(a[0] * 0.125f - m) * inv;
      float p1 = __expf(a[1] * 0.125f - m) * inv;
      float p2 = __expf(a[2] * 0.125f - m) * inv;
      float p3 = __expf(a[3] * 0.125f - m) * inv;
      pa8[i >> 1].u[(i & 1) * 2 + 0] = cvt_pk_bf16(p0, p1);
      pa8[i >> 1].u[(i & 1) * 2 + 1] = cvt_pk_bf16(p2, p3);
    }
    // PV: 4 s-iters x 4 hd-tiles, one 16B B-frag load each (vT2 permuted)
#pragma unroll
    for (int s = 0; s < 4; ++s) {
      const int off = kc + s * 32;
      short8 b0 = *reinterpret_cast<const short8*>(vt0 + off);
      short8 b1 = *reinterpret_cast<const short8*>(vt1 + off);
      short8 b2 = *reinterpret_cast<const short8*>(vt2 + off);
      short8 b3 = *reinterpret_cast<const short8*>(vt3 + off);
      pv0 = mfma16(pa8[s].s, b0, pv0);
      pv1 = mfma16(pa8[s].s, b1, pv1);
      pv2 = mfma16(pa8[s].s, b2, pv2);
      pv3 = mfma16(pa8[s].s, b3, pv3);
    }
    // attn_w store: expand pa8, bpermute repack, full-line nt stores
#pragma unroll
    for (int s = 0; s < 4; ++s) {
      f32x4 X, Y;
      X[0] = bf16lo_f32(pa8[s].u[0]); X[1] = bf16hi_f32(pa8[s].u[0]);
      X[2] = bf16lo_f32(pa8[s].u[1]); X[3] = bf16hi_f32(pa8[s].u[1]);
      Y[0] = bf16lo_f32(pa8[s].u[2]); Y[1] = bf16hi_f32(pa8[s].u[2]);
      Y[2] = bf16lo_f32(pa8[s].u[3]); Y[3] = bf16hi_f32(pa8[s].u[3]);
      f32x4 o0, o1;
#pragma unroll
      for (int cc = 0; cc < 4; ++cc) {
        float x0 = bperm_f32(idx0, X[cc]);
        float y0 = bperm_f32(idx0, Y[cc]);
        o0[cc] = hiq ? y0 : x0;
        float x1 = bperm_f32(idx1, X[cc]);
        float y1 = bperm_f32(idx1, Y[cc]);
        o1[cc] = hiq ? y1 : x1;
      }
      __builtin_nontemporal_store(o0, reinterpret_cast<f32x4*>(arow0 + kc + s * 32));
      __builtin_nontemporal_store(o1, reinterpret_cast<f32x4*>(arow1 + kc + s * 32));
    }
  }

  // ---- hout: lane holds out[q=lg*4+r][hd=ht*16+lr], full k -> no reduce ----
  unsigned short* hb = hout + (size_t)(r0 + lg * 4) * EMB + h * HDIM + lr;
#pragma unroll
  for (int r = 0; r < 4; ++r) {
    hb[(size_t)r * EMB +  0] = f2bf(pv0[r]);
    hb[(size_t)r * EMB + 16] = f2bf(pv1[r]);
    hb[(size_t)r * EMB + 32] = f2bf(pv2[r]);
    hb[(size_t)r * EMB + 48] = f2bf(pv3[r]);
  }
}

extern "C" void kernel_launch(void* const* d_in, const int* in_sizes, int n_in,
                              void* d_out, int out_size, void* d_ws, size_t ws_size,
                              hipStream_t stream) {
  const float* x  = (const float*)d_in[0];
  const float* Wq = (const float*)d_in[1];
  const float* bq = (const float*)d_in[2];
  const float* Wk = (const float*)d_in[3];
  const float* bk = (const float*)d_in[4];
  const float* Wv = (const float*)d_in[5];
  const float* bv = (const float*)d_in[6];
  const float* Wo = (const float*)d_in[7];
  const float* bo = (const float*)d_in[8];
  float* out = (float*)d_out;

  char* ws = (char*)d_ws;
  unsigned short* x_bf  = (unsigned short*)(ws);                 // 8 MiB
  unsigned short* wqkv  = (unsigned short*)(ws + (8ull  << 20)); // 12 MiB
  unsigned short* wo_bf = (unsigned short*)(ws + (20ull << 20)); // 8 MiB
  float*          bqkv  = (float*)         (ws + (28ull << 20)); // 12 KiB
  unsigned short* qkv   = (unsigned short*)(ws + (29ull << 20)); // 12 MiB
  unsigned short* vT    = (unsigned short*)(ws + (41ull << 20)); // 2 MiB
  unsigned short* hout  = (unsigned short*)(ws + (43ull << 20)); // 8 MiB

  k_cvt_all<<<14336, 256, 0, stream>>>(x, Wq, Wk, Wv, Wo, x_bf, wqkv, wo_bf);
  k_bias_cat<<<12, 256, 0, stream>>>(bq, bk, bv, bqkv);

  dim3 g1(16, 24);  // M/128 x N/128
  k_gemm_bt<unsigned short><<<g1, 256, 0, stream>>>(x_bf, wqkv, bqkv, qkv, 2048, 3072, 2048);
  k_vT<<<256, 256, 0, stream>>>(qkv, vT);
  k_attn<<<1024, 256, 0, stream>>>(qkv, vT, out, hout);
  dim3 g2(16, 16);
  k_gemm_bt<float><<<g2, 256, 0, stream>>>(hout, wo_bf, bo, out + (size_t)NHEAD * S_LEN * S_LEN, 2048, 2048, 2048);
}

// Round 9
// 330.069 us; speedup vs baseline: 1.5192x; 1.4286x over previous
//
#include <hip/hip_runtime.h>
#include <stdint.h>

#define S_LEN 2048
#define EMB   2048
#define NHEAD 32
#define HDIM  64
#define QKVN  3072   // 2048 q + 512 k + 512 v
#define KOFF  2048
#define VOFF  2560

typedef __attribute__((ext_vector_type(8))) short short8;
typedef __attribute__((ext_vector_type(4))) short short4v;
typedef __attribute__((ext_vector_type(4))) float f32x4;

__device__ __forceinline__ unsigned short f2bf(float f) {
  union { float f; unsigned u; } v; v.f = f;
  return (unsigned short)((v.u + 0x7fffu + ((v.u >> 16) & 1u)) >> 16);
}

__device__ __forceinline__ f32x4 mfma16(short8 a, short8 b, f32x4 c) {
  return __builtin_amdgcn_mfma_f32_16x16x32_bf16(a, b, c, 0, 0, 0);
}

__device__ __forceinline__ void gload_lds16(const void* g, void* l) {
  __builtin_amdgcn_global_load_lds(
      (const __attribute__((address_space(1))) void*)g,
      (__attribute__((address_space(3))) void*)l, 16, 0, 0);
}

__device__ __forceinline__ unsigned cvt_pk_bf16(float lo, float hi) {
  unsigned r;
  asm("v_cvt_pk_bf16_f32 %0, %1, %2" : "=v"(r) : "v"(lo), "v"(hi));
  return r;
}

__device__ __forceinline__ float bperm_f32(int idx_bytes, float v) {
  int r = __builtin_amdgcn_ds_bpermute(idx_bytes, __builtin_bit_cast(int, v));
  return __builtin_bit_cast(float, r);
}

__device__ __forceinline__ float bf16lo_f32(unsigned u) {
  return __builtin_bit_cast(float, u << 16);
}
__device__ __forceinline__ float bf16hi_f32(unsigned u) {
  return __builtin_bit_cast(float, u & 0xffff0000u);
}

// ---------------- fused fp32 -> bf16 convert (all 5 tensors) ----------------
__global__ __launch_bounds__(256) void k_cvt_all(
    const float* __restrict__ x, const float* __restrict__ Wq,
    const float* __restrict__ Wk, const float* __restrict__ Wv,
    const float* __restrict__ Wo, unsigned short* __restrict__ xb,
    unsigned short* __restrict__ wqkv, unsigned short* __restrict__ wob) {
  long i = (long)(blockIdx.x * blockDim.x + threadIdx.x) * 4;
  const float* src; unsigned short* dst; long off;
  if (i < 4194304L)       { src = x;  dst = xb;             off = i; }
  else if (i < 8388608L)  { src = Wq; dst = wqkv;           off = i - 4194304L; }
  else if (i < 9437184L)  { src = Wk; dst = wqkv + 4194304; off = i - 8388608L; }
  else if (i < 10485760L) { src = Wv; dst = wqkv + 5242880; off = i - 9437184L; }
  else                    { src = Wo; dst = wob;            off = i - 10485760L; }
  float4 v = *reinterpret_cast<const float4*>(src + off);
  short4v o;
  o.x = (short)f2bf(v.x); o.y = (short)f2bf(v.y);
  o.z = (short)f2bf(v.z); o.w = (short)f2bf(v.w);
  *reinterpret_cast<short4v*>(dst + off) = o;
}

__global__ void k_bias_cat(const float* __restrict__ bq, const float* __restrict__ bk,
                           const float* __restrict__ bv, float* __restrict__ dst) {
  int i = blockIdx.x * blockDim.x + threadIdx.x;   // grid covers exactly 3072
  if (i < 2048) dst[i] = bq[i];
  else if (i < 2560) dst[i] = bk[i - 2048];
  else dst[i] = bv[i - 2560];
}

// ---------------- GEMM: C[M,N] = A[M,K] @ B[N,K]^T + bias ----------------
template <typename OUT_T>
__global__ __launch_bounds__(256) void k_gemm_bt(
    const unsigned short* __restrict__ A, const unsigned short* __restrict__ B,
    const float* __restrict__ bias, OUT_T* __restrict__ C, int M, int N, int K) {
  __shared__ unsigned short As[128 * 32];
  __shared__ unsigned short Bs[128 * 32];
  const int t = threadIdx.x;
  const int l = t & 63;
  const int w = t >> 6;
  const int m0 = blockIdx.x * 128;
  const int n0 = blockIdx.y * 128;
  const int wm = w >> 1, wn = w & 1;

  f32x4 acc[4][4] = {};

  const unsigned short* ga0 = A + (size_t)(m0 + (t >> 2)) * K + (t & 3) * 8;
  const unsigned short* ga1 = ga0 + (size_t)64 * K;
  const unsigned short* gb0 = B + (size_t)(n0 + (t >> 2)) * K + (t & 3) * 8;
  const unsigned short* gb1 = gb0 + (size_t)64 * K;
  unsigned short* la0 = As + t * 8;
  unsigned short* la1 = As + 2048 + t * 8;
  unsigned short* lb0 = Bs + t * 8;
  unsigned short* lb1 = Bs + 2048 + t * 8;

  const int lr = l & 15;
  const int lk = (l >> 4) * 8;
  const unsigned short* arow = As + (wm * 64 + lr) * 32 + lk;
  const unsigned short* brow = Bs + (wn * 64 + lr) * 32 + lk;

  for (int k0 = 0; k0 < K; k0 += 32) {
    gload_lds16(ga0, la0);
    gload_lds16(ga1, la1);
    gload_lds16(gb0, lb0);
    gload_lds16(gb1, lb1);
    ga0 += 32; ga1 += 32; gb0 += 32; gb1 += 32;
    __syncthreads();
    short8 af[4], bfv[4];
#pragma unroll
    for (int i = 0; i < 4; i++) {
      af[i]  = *reinterpret_cast<const short8*>(arow + i * 16 * 32);
      bfv[i] = *reinterpret_cast<const short8*>(brow + i * 16 * 32);
    }
#pragma unroll
    for (int i = 0; i < 4; i++)
#pragma unroll
      for (int j = 0; j < 4; j++)
        acc[i][j] = mfma16(af[i], bfv[j], acc[i][j]);
    __syncthreads();
  }

  const int lg = l >> 4;
#pragma unroll
  for (int i = 0; i < 4; i++) {
#pragma unroll
    for (int j = 0; j < 4; j++) {
      int col = n0 + wn * 64 + j * 16 + lr;
      float bb = bias[col];
#pragma unroll
      for (int r = 0; r < 4; r++) {
        int row = m0 + wm * 64 + i * 16 + lg * 4 + r;
        float val = acc[i][j][r] + bb;
        if constexpr (sizeof(OUT_T) == 2)
          C[(size_t)row * N + col] = (OUT_T)f2bf(val);
        else
          C[(size_t)row * N + col] = (OUT_T)val;
      }
    }
  }
}

// ---------------- K compaction into swizzled per-(group,chunk) tiles --------
// kc[g][c] = 16KB tile: element(row in [0,128), col in [0,64)) at byte
//   (row*128 + col*2) ^ ((row&7)<<4)
// so that a LINEAR 16KB gload_lds stage yields bank-floor ds_read_b128 frags.
__global__ __launch_bounds__(256) void k_kc(const unsigned short* __restrict__ qkv,
                                            unsigned short* __restrict__ kc) {
  const int gi = blockIdx.x >> 4;       // group
  const int c  = blockIdx.x & 15;       // k-chunk
  const int t = threadIdx.x;
  const int row = t & 127;
  const int part = t >> 7;              // 0/1 (cols 0-31 / 32-63)
  const unsigned short* src =
      qkv + (size_t)(c * 128 + row) * QKVN + KOFF + gi * 64 + part * 32;
  char* dst = (char*)kc + ((size_t)(gi * 16 + c) << 14);
  const int swz = (row & 7) << 4;
#pragma unroll
  for (int j = 0; j < 4; ++j) {
    short8 v = *reinterpret_cast<const short8*>(src + j * 8);
    int b = (row * 128 + part * 64 + j * 16) ^ swz;
    *reinterpret_cast<short8*>(dst + b) = v;
  }
}

// ---------------- V transpose -> swizzled per-(group,chunk) tiles -----------
// vt[g][c] = 16KB tile: element(row=gd in [0,64), colp in [0,128) POST-sigma)
// at byte (row*256 + colp*2) ^ ((row&7)<<4). sigma packs PV B-frags so one
// 16B read = one MFMA B operand (kappa relabeling, verified v8).
__global__ __launch_bounds__(256) void k_vT(const unsigned short* __restrict__ qkv,
                                            unsigned short* __restrict__ vt) {
  __shared__ unsigned short tile[64][72];
  const int t = threadIdx.x;
  const int p0 = (blockIdx.x & 31) * 64;
  const int g0 = (blockIdx.x >> 5) * 64;
  {
    const int pl = t >> 3;
    const int gl = (t & 7) * 8;
#pragma unroll
    for (int i = 0; i < 2; i++) {
      int p = pl + i * 32;
      short8 v = *reinterpret_cast<const short8*>(qkv + (size_t)(p0 + p) * QKVN + VOFF + g0 + gl);
#pragma unroll
      for (int j = 0; j < 8; j++) tile[p][gl + j] = (unsigned short)v[j];
    }
  }
  __syncthreads();
  {
    const int gr = t >> 3;
    const int pc = (t & 7) * 8;
    const int cb = pc & ~31;
    const int rbase = pc & 31;
    const int chunk = p0 >> 7;
    const int colin = (p0 & 64) + pc;    // col within 128-chunk
    const int grp = g0 >> 6;
#pragma unroll
    for (int i = 0; i < 2; i++) {
      int g = gr + i * 32;               // row in tile (gd within group)
      short8 o;
#pragma unroll
      for (int j = 0; j < 8; j++) {
        int rp = rbase + j;
        int q8 = rp >> 3, jj = rp & 7;
        int src = cb + ((jj < 4) ? (q8 * 4 + jj) : (16 + q8 * 4 + (jj - 4)));
        o[j] = (short)tile[src][g];
      }
      int b = (g * 256 + colin * 2) ^ ((g & 7) << 4);
      *reinterpret_cast<short8*>(
          (char*)vt + (((size_t)(grp * 16 + chunk)) << 14) + b) = o;
    }
  }
}

// ---------------- fused attention v9: LDS-staged tiles, zero gathers --------
// Block = 512 thr (8 waves) = one (group, 8 wave-units); wave = (head, 16
// q-rows) x full k (so softmax/PV/store machinery is VERBATIM v8 -- no
// cross-wave reduce). Groups pinned to XCDs (g = bid&7). Per 128-col chunk:
// stage 16KB K (+16KB V in pass B) tiles via coalesced global_load_lds, read
// MFMA frags from LDS at the b128 bank floor (XOR swizzle baked into tiles).
// This removes the 16-line-per-instruction K/vT gathers that bound v5-v8
// (TA/L1 transaction throughput), ~7x fewer line-touches per CU.
// Barrier discipline: bottom barrier = lgkmcnt-only (stores drain past it);
// stores issue before PV so PV's LDS-only phase hides their latency.
__global__ __launch_bounds__(512, 4) void k_attn(
    const unsigned short* __restrict__ qkv, const unsigned short* __restrict__ kc,
    const unsigned short* __restrict__ vt, float* __restrict__ attn_w,
    unsigned short* __restrict__ hout) {
  __shared__ unsigned short Kt[8192];   // 16 KB
  __shared__ unsigned short Vt[8192];   // 16 KB
  const int t = threadIdx.x;
  const int l = t & 63;
  const int w = t >> 6;                    // wave 0..7
  const int g = blockIdx.x & 7;            // group == XCD (round-robin)
  const int bi = blockIdx.x >> 3;          // 0..63
  const int unit = bi * 8 + w;             // 0..511
  const int h = g * 4 + (unit & 3);        // head
  const int r0 = (unit >> 2) * 16;         // q-row base
  const int lr = l & 15;
  const int lg = l >> 4;                   // 0..3
  const int lk = lg * 8;
  const int swz = (lr & 7) << 4;

  // Q fragment = B operand of QK^T (rows r0+lr)
  const unsigned short* qbase = qkv + (size_t)(r0 + lr) * QKVN + h * HDIM + lk;
  const short8 bq0 = *reinterpret_cast<const short8*>(qbase);
  const short8 bq1 = *reinterpret_cast<const short8*>(qbase + 32);

  const char* kcg = (const char*)kc + ((size_t)(g * 16) << 14);
  const char* vtg = (const char*)vt + ((size_t)(g * 16) << 14);
  char* kdst = (char*)Kt;
  char* vdst = (char*)Vt;
  const char* kldb = (const char*)Kt;
  const char* vldb = (const char*)Vt;

#define STAGE_K(c)                                                      \
  { const char* s_ = kcg + ((size_t)(c) << 14);                         \
    gload_lds16(s_ + t * 16, kdst + t * 16);                            \
    gload_lds16(s_ + 8192 + t * 16, kdst + 8192 + t * 16); }
#define STAGE_V(c)                                                      \
  { const char* s_ = vtg + ((size_t)(c) << 14);                         \
    gload_lds16(s_ + t * 16, vdst + t * 16);                            \
    gload_lds16(s_ + 8192 + t * 16, vdst + 8192 + t * 16); }
#define LGKM_BAR()                                                      \
  asm volatile("s_waitcnt lgkmcnt(0)\n\ts_barrier" ::: "memory");       \
  __builtin_amdgcn_sched_barrier(0);

  // ---- pass A: online row max + sum; K tiles from LDS ----
  float m = -1e30f, sm = 0.f;
  STAGE_K(0);
  __syncthreads();
  for (int c = 0; c < 16; ++c) {
    f32x4 acc[8];
#pragma unroll
    for (int i = 0; i < 8; ++i) {
      int rb = ((i * 16 + lr) << 7) + (lg << 4);
      short8 a0 = *reinterpret_cast<const short8*>(kldb + (rb ^ swz));
      short8 a1 = *reinterpret_cast<const short8*>(kldb + ((rb + 64) ^ swz));
      f32x4 a = {};
      a = mfma16(a0, bq0, a);
      a = mfma16(a1, bq1, a);
      acc[i] = a * 0.125f;
    }
    float mc = -1e30f;
#pragma unroll
    for (int i = 0; i < 8; ++i)
      mc = fmaxf(mc, fmaxf(fmaxf(acc[i][0], acc[i][1]), fmaxf(acc[i][2], acc[i][3])));
    mc = fmaxf(mc, __shfl_xor(mc, 16, 64));
    mc = fmaxf(mc, __shfl_xor(mc, 32, 64));
    float nm = fmaxf(m, mc);
    float ps = 0.f;
#pragma unroll
    for (int i = 0; i < 8; ++i) {
#pragma unroll
      for (int r = 0; r < 4; ++r) ps += __expf(acc[i][r] - nm);
    }
    ps += __shfl_xor(ps, 16, 64);
    ps += __shfl_xor(ps, 32, 64);
    sm = sm * __expf(m - nm) + ps;
    m = nm;
    LGKM_BAR();                       // all waves done reading Kt
    if (c < 15) STAGE_K(c + 1);
    __syncthreads();                  // vmcnt(0): next tile ready
  }
  const float inv = 1.0f / sm;

  // ---- pass B: recompute P, store attn, PV ----
  f32x4 pv0 = {}, pv1 = {}, pv2 = {}, pv3 = {};
  const int jj = l & 7;
  const int rown = l >> 3;
  const int idx0 = ((l & 3) * 16 + rown) * 4;   // bperm source (rows 0-7)
  const int idx1 = idx0 + 32;                   // rows 8-15
  const bool hiq = (l & 4) != 0;
  float* arow0 = attn_w + (size_t)h * S_LEN * S_LEN
               + (size_t)(r0 + rown) * S_LEN + jj * 4;
  float* arow1 = arow0 + 8 * S_LEN;

  STAGE_K(0);
  STAGE_V(0);
  __syncthreads();
  for (int c = 0; c < 16; ++c) {
    const int kcol = c * 128;
    union A8 { short8 s; unsigned u[4]; } pa8[4];
#pragma unroll
    for (int i = 0; i < 8; ++i) {
      int rb = ((i * 16 + lr) << 7) + (lg << 4);
      short8 a0 = *reinterpret_cast<const short8*>(kldb + (rb ^ swz));
      short8 a1 = *reinterpret_cast<const short8*>(kldb + ((rb + 64) ^ swz));
      f32x4 a = {};
      a = mfma16(a0, bq0, a);
      a = mfma16(a1, bq1, a);
      float p0 = __expf(a[0] * 0.125f - m) * inv;
      float p1 = __expf(a[1] * 0.125f - m) * inv;
      float p2 = __expf(a[2] * 0.125f - m) * inv;
      float p3 = __expf(a[3] * 0.125f - m) * inv;
      pa8[i >> 1].u[(i & 1) * 2 + 0] = cvt_pk_bf16(p0, p1);
      pa8[i >> 1].u[(i & 1) * 2 + 1] = cvt_pk_bf16(p2, p3);
    }
    // attn_w stores first (fire-and-forget; PV's LDS phase hides the drain)
#pragma unroll
    for (int s = 0; s < 4; ++s) {
      f32x4 X, Y;
      X[0] = bf16lo_f32(pa8[s].u[0]); X[1] = bf16hi_f32(pa8[s].u[0]);
      X[2] = bf16lo_f32(pa8[s].u[1]); X[3] = bf16hi_f32(pa8[s].u[1]);
      Y[0] = bf16lo_f32(pa8[s].u[2]); Y[1] = bf16hi_f32(pa8[s].u[2]);
      Y[2] = bf16lo_f32(pa8[s].u[3]); Y[3] = bf16hi_f32(pa8[s].u[3]);
      f32x4 o0, o1;
#pragma unroll
      for (int cc = 0; cc < 4; ++cc) {
        float x0 = bperm_f32(idx0, X[cc]);
        float y0 = bperm_f32(idx0, Y[cc]);
        o0[cc] = hiq ? y0 : x0;
        float x1 = bperm_f32(idx1, X[cc]);
        float y1 = bperm_f32(idx1, Y[cc]);
        o1[cc] = hiq ? y1 : x1;
      }
      __builtin_nontemporal_store(o0, reinterpret_cast<f32x4*>(arow0 + kcol + s * 32));
      __builtin_nontemporal_store(o1, reinterpret_cast<f32x4*>(arow1 + kcol + s * 32));
    }
    // PV from Vt (LDS): B-frag = one swizzled 16B read per (s, hd-tile)
#pragma unroll
    for (int s = 0; s < 4; ++s) {
      int cbyte = s * 64 + (lg << 4);
      short8 b0 = *reinterpret_cast<const short8*>(vldb + ((((lr) << 8) + cbyte) ^ swz));
      short8 b1 = *reinterpret_cast<const short8*>(vldb + ((((16 + lr) << 8) + cbyte) ^ swz));
      short8 b2 = *reinterpret_cast<const short8*>(vldb + ((((32 + lr) << 8) + cbyte) ^ swz));
      short8 b3 = *reinterpret_cast<const short8*>(vldb + ((((48 + lr) << 8) + cbyte) ^ swz));
      pv0 = mfma16(pa8[s].s, b0, pv0);
      pv1 = mfma16(pa8[s].s, b1, pv1);
      pv2 = mfma16(pa8[s].s, b2, pv2);
      pv3 = mfma16(pa8[s].s, b3, pv3);
    }
    LGKM_BAR();                       // LDS reads done; stores keep draining
    if (c < 15) { STAGE_K(c + 1); STAGE_V(c + 1); }
    __syncthreads();
  }

  // ---- hout: lane holds out[q=lg*4+r][hd=ht*16+lr]; full k -> no reduce ----
  unsigned short* hb = hout + (size_t)(r0 + lg * 4) * EMB + h * HDIM + lr;
#pragma unroll
  for (int r = 0; r < 4; ++r) {
    hb[(size_t)r * EMB +  0] = f2bf(pv0[r]);
    hb[(size_t)r * EMB + 16] = f2bf(pv1[r]);
    hb[(size_t)r * EMB + 32] = f2bf(pv2[r]);
    hb[(size_t)r * EMB + 48] = f2bf(pv3[r]);
  }
#undef STAGE_K
#undef STAGE_V
#undef LGKM_BAR
}

extern "C" void kernel_launch(void* const* d_in, const int* in_sizes, int n_in,
                              void* d_out, int out_size, void* d_ws, size_t ws_size,
                              hipStream_t stream) {
  const float* x  = (const float*)d_in[0];
  const float* Wq = (const float*)d_in[1];
  const float* bq = (const float*)d_in[2];
  const float* Wk = (const float*)d_in[3];
  const float* bk = (const float*)d_in[4];
  const float* Wv = (const float*)d_in[5];
  const float* bv = (const float*)d_in[6];
  const float* Wo = (const float*)d_in[7];
  const float* bo = (const float*)d_in[8];
  float* out = (float*)d_out;

  char* ws = (char*)d_ws;
  unsigned short* x_bf  = (unsigned short*)(ws);                 // 8 MiB
  unsigned short* wqkv  = (unsigned short*)(ws + (8ull  << 20)); // 12 MiB
  unsigned short* wo_bf = (unsigned short*)(ws + (20ull << 20)); // 8 MiB
  float*          bqkv  = (float*)         (ws + (28ull << 20)); // 12 KiB
  unsigned short* qkv   = (unsigned short*)(ws + (29ull << 20)); // 12 MiB
  unsigned short* vt_b  = (unsigned short*)(ws + (41ull << 20)); // 2 MiB
  unsigned short* hout  = (unsigned short*)(ws + (43ull << 20)); // 8 MiB
  unsigned short* kc_b  = (unsigned short*)(ws + (51ull << 20)); // 2 MiB

  k_cvt_all<<<14336, 256, 0, stream>>>(x, Wq, Wk, Wv, Wo, x_bf, wqkv, wo_bf);
  k_bias_cat<<<12, 256, 0, stream>>>(bq, bk, bv, bqkv);

  dim3 g1(16, 24);  // M/128 x N/128
  k_gemm_bt<unsigned short><<<g1, 256, 0, stream>>>(x_bf, wqkv, bqkv, qkv, 2048, 3072, 2048);
  k_kc<<<128, 256, 0, stream>>>(qkv, kc_b);
  k_vT<<<256, 256, 0, stream>>>(qkv, vt_b);
  k_attn<<<512, 512, 0, stream>>>(qkv, kc_b, vt_b, out, hout);
  dim3 g2(16, 16);
  k_gemm_bt<float><<<g2, 256, 0, stream>>>(hout, wo_bf, bo, out + (size_t)NHEAD * S_LEN * S_LEN, 2048, 2048, 2048);
}